// Round 15
// baseline (755.962 us; speedup 1.0000x reference)
//
#include <hip/hip_runtime.h>
#include <math.h>

#define BB 64
#define TT 2048
#define FF 128
#define HH 32
#define GG 128  // 4*H

// gate-column prescale: sigma(a) = rcp(1 + exp2(S1*a)), tanh(a) = 2*rcp(1+exp2(S2*a))-1
#define S1f (-1.4426950408889634f)  // -log2(e)
#define S2f (-2.8853900817779268f)  // -2*log2(e)

typedef _Float16 half2_t __attribute__((ext_vector_type(2)));

__device__ __forceinline__ unsigned h2u(half2_t v) {
    unsigned u; __builtin_memcpy(&u, &v, 4); return u;
}
__device__ __forceinline__ half2_t u2h(unsigned u) {
    half2_t v; __builtin_memcpy(&v, &u, 4); return v;
}
__device__ __forceinline__ half2_t pkrtz(float a, float b) {
    auto r = __builtin_amdgcn_cvt_pkrtz(a, b);  // __fp16 vec2, same bits
    half2_t v; __builtin_memcpy(&v, &r, 4); return v;
}
__device__ __forceinline__ float rcp_(float x) { return __builtin_amdgcn_rcpf(x); }
__device__ __forceinline__ float exp2_(float x) { return __builtin_amdgcn_exp2f(x); }
__device__ __forceinline__ float fdot2_(half2_t a, half2_t b, float c) {
    return __builtin_amdgcn_fdot2(a, b, c, false);
}

// DPP lane shuffles (within rows of 16 / quads); bound_ctrl=1, all rows/banks
#define DPP_(x, ctrl) \
    ((unsigned)__builtin_amdgcn_mov_dpp((int)(x), (ctrl), 0xF, 0xF, true))
#define CTRL_XOR1 0xB1  // quad_perm [1,0,3,2]
#define CTRL_XOR2 0x4E  // quad_perm [2,3,0,1]
// ds_swizzle bit-mode xor16 within 32-lane groups: (16<<10)|0x1F
#define SWZ16_(x) ((unsigned)__builtin_amdgcn_ds_swizzle((int)(x), 0x401F))

#if __has_builtin(__builtin_amdgcn_permlane16_swap)
#define HAVE_PL16 1
#else
#define HAVE_PL16 0
#endif

// interleave ladders: zero-instruction volatile asm pinning both chains'
// fresh values; mutual volatile ordering prevents the scheduler from
// sinking one chain's dataflow after the other's.
#define LAD2(a, b) asm volatile("" : "+v"(a), "+v"(b))
#define LAD4(a, b, c, d) asm volatile("" : "+v"(a), "+v"(b), "+v"(c), "+v"(d))
#define LAD8(a, b, c, d, e, f, g, h) \
    asm volatile("" : "+v"(a), "+v"(b), "+v"(c), "+v"(d), \
                      "+v"(e), "+v"(f), "+v"(g), "+v"(h))

// 16-reg all-gather: depth-5 tree (pl16swap + row-local rors). Discovery
// (identical ops on the lane index) makes the exact permutation irrelevant.
__device__ __forceinline__ void gather_tree(unsigned v0, unsigned g[16]) {
#if HAVE_PL16
    unsigned v1 = DPP_(v0, CTRL_XOR2);
    auto sw = __builtin_amdgcn_permlane16_swap(v0, v1, false, false);
    unsigned s0 = (unsigned)sw[0], s1 = (unsigned)sw[1];
#else
    unsigned s0 = v0;
    unsigned s1 = SWZ16_(v0);
#endif
    g[0] = s0;                 g[1] = s1;
    g[2]  = DPP_(s0, 0x122);   g[3]  = DPP_(s1, 0x122);
    g[4]  = DPP_(s0, 0x124);   g[5]  = DPP_(s1, 0x124);
    g[6]  = DPP_(s0, 0x126);   g[7]  = DPP_(s1, 0x126);
    g[8]  = DPP_(s0, 0x128);   g[9]  = DPP_(s1, 0x128);
    g[10] = DPP_(s0, 0x12A);   g[11] = DPP_(s1, 0x12A);
    g[12] = DPP_(s0, 0x12C);   g[13] = DPP_(s1, 0x12C);
    g[14] = DPP_(s0, 0x12E);   g[15] = DPP_(s1, 0x12E);
}

// ---- Kernel 1: xg2[b][j][t] = half2( S*(X@Wx+b)[col j], S*(X@Wx+b)[col j+64] )
// fp16-fdot2 inner loop: X and Wx staged as packed K-pairs in LDS.
__global__ __launch_bounds__(256) void xg_gemm(const float* __restrict__ X,
                                               const float* __restrict__ Wx,
                                               const float* __restrict__ bias,
                                               unsigned* __restrict__ xg2) {
    __shared__ unsigned XLh[64][16];
    __shared__ unsigned WLh[16][128];
    const int tid = threadIdx.x;
    const int row0 = blockIdx.x * 64;
    const int j0 = (tid & 15) * 4;
    const int r0 = (tid >> 4) * 4;

    float acc[4][8];
#pragma unroll
    for (int r = 0; r < 4; ++r)
#pragma unroll
        for (int jj = 0; jj < 8; ++jj) acc[r][jj] = 0.f;

    for (int f0 = 0; f0 < FF; f0 += 32) {
        __syncthreads();
        {
            const int jq = (tid & 31) * 4;
#pragma unroll
            for (int qq = 0; qq < 2; ++qq) {
                const int q = (tid >> 5) + qq * 8;
                float4 wa = *(const float4*)(Wx + (size_t)(f0 + 2 * q) * GG + jq);
                float4 wb = *(const float4*)(Wx + (size_t)(f0 + 2 * q + 1) * GG + jq);
                WLh[q][jq + 0] = h2u(pkrtz(wa.x, wb.x));
                WLh[q][jq + 1] = h2u(pkrtz(wa.y, wb.y));
                WLh[q][jq + 2] = h2u(pkrtz(wa.z, wb.z));
                WLh[q][jq + 3] = h2u(pkrtz(wa.w, wb.w));
            }
        }
        {
            int lin = tid * 4;
            int row = lin >> 5, fi = lin & 31;
            float4 x = *(const float4*)(X + (size_t)(row0 + row) * FF + f0 + fi);
            XLh[row][(fi >> 1) + 0] = h2u(pkrtz(x.x, x.y));
            XLh[row][(fi >> 1) + 1] = h2u(pkrtz(x.z, x.w));
            lin = (tid + 256) * 4;
            row = lin >> 5; fi = lin & 31;
            x = *(const float4*)(X + (size_t)(row0 + row) * FF + f0 + fi);
            XLh[row][(fi >> 1) + 0] = h2u(pkrtz(x.x, x.y));
            XLh[row][(fi >> 1) + 1] = h2u(pkrtz(x.z, x.w));
        }
        __syncthreads();
#pragma unroll 4
        for (int q = 0; q < 16; ++q) {
            half2_t xv[4];
#pragma unroll
            for (int r = 0; r < 4; ++r) xv[r] = u2h(XLh[r0 + r][q]);
            uint4 w0 = *(uint4*)&WLh[q][j0];
            uint4 w1 = *(uint4*)&WLh[q][j0 + 64];
            unsigned wj[8] = {w0.x, w0.y, w0.z, w0.w, w1.x, w1.y, w1.z, w1.w};
#pragma unroll
            for (int r = 0; r < 4; ++r)
#pragma unroll
                for (int jj = 0; jj < 8; ++jj)
                    acc[r][jj] = fdot2_(xv[r], u2h(wj[jj]), acc[r][jj]);
        }
    }
    const int b  = row0 >> 11;
    const int t0 = (row0 & 2047) + r0;
#pragma unroll
    for (int jj = 0; jj < 4; ++jj) {
        const int j = j0 + jj;
        const float bX = bias[j];
        const float bY = bias[j + 64];
        const float sY = (j < 32) ? S2f : S1f;
        uint4 o;
        o.x = h2u(pkrtz((acc[0][jj] + bX) * S1f, (acc[0][jj + 4] + bY) * sY));
        o.y = h2u(pkrtz((acc[1][jj] + bX) * S1f, (acc[1][jj + 4] + bY) * sY));
        o.z = h2u(pkrtz((acc[2][jj] + bX) * S1f, (acc[2][jj + 4] + bY) * sY));
        o.w = h2u(pkrtz((acc[3][jj] + bX) * S1f, (acc[3][jj + 4] + bY) * sY));
        *(uint4*)(xg2 + (size_t)(b * 64 + j) * TT + t0) = o;
    }
}

// ---- Kernel 2: LSTM scan, TWO chains per wave, ladder-interleaved ---------
// Block bid handles batches 2*bid (A) and 2*bid+1 (B), round-13 step
// structure each. Volatile-asm ladders between phases force both dataflows
// to stay co-live so B's issue fills A's dependency stalls and vice versa.
__global__ __launch_bounds__(64) void lstm_rec(const unsigned* __restrict__ xg2,
                                               const float* __restrict__ Wh,
                                               const float* __restrict__ Wd,
                                               const float* __restrict__ bd,
                                               float* __restrict__ out) {
    const int l = threadIdx.x;
    const int m = l & 31;
    const bool lo = (l < HH);
    const int b0 = blockIdx.x * 2;

    unsigned iv[16];
    gather_tree((unsigned)m, iv);

    const float scx = S1f;
    const float scy = lo ? S2f : S1f;
    half2_t whx[16], why[16];
#pragma unroll
    for (int r = 0; r < 16; ++r) {
        const int p  = (int)(iv[r] & 31u);
        const int p2 = p ^ 1;
        whx[r] = pkrtz(Wh[p * GG + l] * scx,       Wh[p2 * GG + l] * scx);
        why[r] = pkrtz(Wh[p * GG + l + 64] * scy,  Wh[p2 * GG + l + 64] * scy);
    }

    const float A1 = lo ? 2.f : 1.f;
    const float B1 = lo ? -1.f : 0.f;

    float hA = 0.f, cA = 0.f, hB = 0.f, cB = 0.f;

    const unsigned* pA = xg2 + (size_t)(b0 * 64 + l) * TT;
    const unsigned* pB = xg2 + (size_t)((b0 + 1) * 64 + l) * TT;

    uint4 curA = *(const uint4*)(pA);
    uint4 curB = *(const uint4*)(pB);
    uint4 nxtA = *(const uint4*)(pA + 4);
    uint4 nxtB = *(const uint4*)(pB + 4);

    auto dual_step = [&](unsigned wA, unsigned wB)
        __attribute__((always_inline)) {
        // ---- phase 1: gather bases ----
        unsigned hnA = DPP_(__float_as_uint(hA), CTRL_XOR1);
        unsigned hnB = DPP_(__float_as_uint(hB), CTRL_XOR1);
        unsigned g0A = h2u(pkrtz(hA, __uint_as_float(hnA)));
        unsigned g0B = h2u(pkrtz(hB, __uint_as_float(hnB)));
#if HAVE_PL16
        unsigned v1A = DPP_(g0A, CTRL_XOR2);
        unsigned v1B = DPP_(g0B, CTRL_XOR2);
        auto swA = __builtin_amdgcn_permlane16_swap(g0A, v1A, false, false);
        auto swB = __builtin_amdgcn_permlane16_swap(g0B, v1B, false, false);
        unsigned s0A = (unsigned)swA[0], s1A = (unsigned)swA[1];
        unsigned s0B = (unsigned)swB[0], s1B = (unsigned)swB[1];
#else
        unsigned s0A = g0A, s1A = SWZ16_(g0A);
        unsigned s0B = g0B, s1B = SWZ16_(g0B);
#endif
        LAD4(s0A, s1A, s0B, s1B);

        // ---- phase 2: rors + matvec, interleaved (literal DPP ctrls) ----
        half2_t xvA = u2h(wA);
        half2_t xvB = u2h(wB);
        float axA[4] = {(float)xvA[0], 0.f, 0.f, 0.f};
        float ayA[4] = {(float)xvA[1], 0.f, 0.f, 0.f};
        float axB[4] = {(float)xvB[0], 0.f, 0.f, 0.f};
        float ayB[4] = {(float)xvB[1], 0.f, 0.f, 0.f};
        // r = 0,1 (s0, s1 directly)
        {
            half2_t hA0 = u2h(s0A), hA1 = u2h(s1A);
            half2_t hB0 = u2h(s0B), hB1 = u2h(s1B);
            axA[0] = fdot2_(hA0, whx[0], axA[0]);
            axB[0] = fdot2_(hB0, whx[0], axB[0]);
            ayA[0] = fdot2_(hA0, why[0], ayA[0]);
            ayB[0] = fdot2_(hB0, why[0], ayB[0]);
            axA[1] = fdot2_(hA1, whx[1], axA[1]);
            axB[1] = fdot2_(hB1, whx[1], axB[1]);
            ayA[1] = fdot2_(hA1, why[1], ayA[1]);
            ayB[1] = fdot2_(hB1, why[1], ayB[1]);
        }
        LAD8(axA[0], ayA[0], axB[0], ayB[0], axA[1], ayA[1], axB[1], ayB[1]);

#define ROR_LEVEL(CTRL, R)                                                  \
        {                                                                   \
            unsigned gA0 = DPP_(s0A, (CTRL));                               \
            unsigned gA1 = DPP_(s1A, (CTRL));                               \
            unsigned gB0 = DPP_(s0B, (CTRL));                               \
            unsigned gB1 = DPP_(s1B, (CTRL));                               \
            axA[(R) & 3] = fdot2_(u2h(gA0), whx[(R)], axA[(R) & 3]);        \
            axB[(R) & 3] = fdot2_(u2h(gB0), whx[(R)], axB[(R) & 3]);        \
            ayA[(R) & 3] = fdot2_(u2h(gA0), why[(R)], ayA[(R) & 3]);        \
            ayB[(R) & 3] = fdot2_(u2h(gB0), why[(R)], ayB[(R) & 3]);        \
            axA[((R) + 1) & 3] = fdot2_(u2h(gA1), whx[(R) + 1], axA[((R) + 1) & 3]); \
            axB[((R) + 1) & 3] = fdot2_(u2h(gB1), whx[(R) + 1], axB[((R) + 1) & 3]); \
            ayA[((R) + 1) & 3] = fdot2_(u2h(gA1), why[(R) + 1], ayA[((R) + 1) & 3]); \
            ayB[((R) + 1) & 3] = fdot2_(u2h(gB1), why[(R) + 1], ayB[((R) + 1) & 3]); \
        }

        ROR_LEVEL(0x122, 2)
        ROR_LEVEL(0x124, 4)
        LAD8(axA[0], ayA[1], axB[0], ayB[1], axA[2], ayA[3], axB[2], ayB[3]);
        ROR_LEVEL(0x126, 6)
        ROR_LEVEL(0x128, 8)
        LAD8(axA[0], ayA[1], axB[0], ayB[1], axA[2], ayA[3], axB[2], ayB[3]);
        ROR_LEVEL(0x12A, 10)
        ROR_LEVEL(0x12C, 12)
        ROR_LEVEL(0x12E, 14)
        LAD8(axA[0], ayA[1], axB[0], ayB[1], axA[2], ayA[3], axB[2], ayB[3]);
#undef ROR_LEVEL

        float a0A = (axA[0] + axA[1]) + (axA[2] + axA[3]);
        float a0B = (axB[0] + axB[1]) + (axB[2] + axB[3]);
        float a1A = (ayA[0] + ayA[1]) + (ayA[2] + ayA[3]);
        float a1B = (ayB[0] + ayB[1]) + (ayB[2] + ayB[3]);
        LAD4(a0A, a1A, a0B, a1B);

        // ---- phase 3: activations ----
        float e0A = exp2_(a0A);
        float e0B = exp2_(a0B);
        float e1A = exp2_(a1A);
        float e1B = exp2_(a1B);
        LAD4(e0A, e1A, e0B, e1B);
        float act0A = rcp_(1.f + e0A);
        float act0B = rcp_(1.f + e0B);
        float act1A = fmaf(A1, rcp_(1.f + e1A), B1);
        float act1B = fmaf(A1, rcp_(1.f + e1B), B1);
        LAD4(act0A, act1A, act0B, act1B);

        // ---- phase 4: select-free gate broadcast + c/h updates ----
        auto sw0A = __builtin_amdgcn_permlane32_swap(__float_as_uint(act0A),
                                                     __float_as_uint(act0A), false, false);
        auto sw0B = __builtin_amdgcn_permlane32_swap(__float_as_uint(act0B),
                                                     __float_as_uint(act0B), false, false);
        auto sw1A = __builtin_amdgcn_permlane32_swap(__float_as_uint(act1A),
                                                     __float_as_uint(act1A), false, false);
        auto sw1B = __builtin_amdgcn_permlane32_swap(__float_as_uint(act1B),
                                                     __float_as_uint(act1B), false, false);
        float iA = __uint_as_float(sw0A[0]);
        float fA = __uint_as_float(sw0A[1]);
        float gA = __uint_as_float(sw1A[0]);
        float oA = __uint_as_float(sw1A[1]);
        float iB = __uint_as_float(sw0B[0]);
        float fB = __uint_as_float(sw0B[1]);
        float gB = __uint_as_float(sw1B[0]);
        float oB = __uint_as_float(sw1B[1]);
        LAD8(iA, fA, gA, oA, iB, fB, gB, oB);
        cA = fmaf(fA, cA, iA * gA);
        cB = fmaf(fB, cB, iB * gB);
        LAD2(cA, cB);
        float ecA = exp2_(cA * S2f);
        float ecB = exp2_(cB * S2f);
        LAD2(ecA, ecB);
        float tcA = fmaf(2.f, rcp_(1.f + ecA), -1.f);
        float tcB = fmaf(2.f, rcp_(1.f + ecB), -1.f);
        hA = oA * tcA;
        hB = oB * tcB;
        LAD4(hA, cA, hB, cB);
    };

#pragma unroll 1
    for (int t4 = 0; t4 < TT; t4 += 4) {
        uint4 uA = curA, uB = curB;
        curA = nxtA; curB = nxtB;
        if (t4 + 8 < TT) {
            nxtA = *(const uint4*)(pA + t4 + 8);
            nxtB = *(const uint4*)(pB + t4 + 8);
        }
        dual_step(uA.x, uB.x);
        dual_step(uA.y, uB.y);
        dual_step(uA.z, uB.z);
        dual_step(uA.w, uB.w);
    }

    const float wd = Wd[m];
    float ca = hA * wd;
    float cb = hB * wd;
#pragma unroll
    for (int off = 32; off >= 1; off >>= 1) {
        ca += __shfl_xor(ca, off, 64);
        cb += __shfl_xor(cb, off, 64);
    }
    if (l == 0) {
        out[b0]     = fmaf(0.5f, ca, bd[0]);
        out[b0 + 1] = fmaf(0.5f, cb, bd[0]);
    }
}

extern "C" void kernel_launch(void* const* d_in, const int* in_sizes, int n_in,
                              void* d_out, int out_size, void* d_ws, size_t ws_size,
                              hipStream_t stream) {
    const float* X    = (const float*)d_in[0];
    const float* Wx   = (const float*)d_in[1];
    const float* Wh   = (const float*)d_in[2];
    const float* bias = (const float*)d_in[3];
    const float* Wd   = (const float*)d_in[4];
    const float* bd   = (const float*)d_in[5];
    float* out = (float*)d_out;
    unsigned* xg2 = (unsigned*)d_ws;  // [64][64][2048] half2-pairs = 32 MB

    hipLaunchKernelGGL(xg_gemm, dim3((BB * TT) / 64), dim3(256), 0, stream,
                       X, Wx, bias, xg2);
    hipLaunchKernelGGL(lstm_rec, dim3(BB / 2), dim3(64), 0, stream,
                       xg2, Wh, Wd, bd, out);
}

// Round 16
// 595.969 us; speedup vs baseline: 1.2685x; 1.2685x over previous
//
#include <hip/hip_runtime.h>
#include <math.h>

#define BB 64
#define TT 2048
#define FF 128
#define HH 32
#define GG 128  // 4*H
#define NTILE 32           // tiles of 64 timesteps per batch
#define FLAG_OFF (48u * 1024u * 1024u)

// gate-column prescale: sigma(a) = rcp(1 + exp2(S1*a)), tanh(a) = 2*rcp(1+exp2(S2*a))-1
#define S1f (-1.4426950408889634f)  // -log2(e)
#define S2f (-2.8853900817779268f)  // -2*log2(e)

typedef _Float16 half2_t __attribute__((ext_vector_type(2)));

__device__ __forceinline__ unsigned h2u(half2_t v) {
    unsigned u; __builtin_memcpy(&u, &v, 4); return u;
}
__device__ __forceinline__ half2_t u2h(unsigned u) {
    half2_t v; __builtin_memcpy(&v, &u, 4); return v;
}
__device__ __forceinline__ half2_t pkrtz(float a, float b) {
    auto r = __builtin_amdgcn_cvt_pkrtz(a, b);  // __fp16 vec2, same bits
    half2_t v; __builtin_memcpy(&v, &r, 4); return v;
}
__device__ __forceinline__ float rcp_(float x) { return __builtin_amdgcn_rcpf(x); }
__device__ __forceinline__ float exp2_(float x) { return __builtin_amdgcn_exp2f(x); }
__device__ __forceinline__ float fdot2_(half2_t a, half2_t b, float c) {
    return __builtin_amdgcn_fdot2(a, b, c, false);
}

// DPP lane shuffles (within rows of 16 / quads); bound_ctrl=1, all rows/banks
#define DPP_(x, ctrl) \
    ((unsigned)__builtin_amdgcn_mov_dpp((int)(x), (ctrl), 0xF, 0xF, true))
#define CTRL_XOR1 0xB1  // quad_perm [1,0,3,2]
#define CTRL_XOR2 0x4E  // quad_perm [2,3,0,1]
// ds_swizzle bit-mode xor16 within 32-lane groups: (16<<10)|0x1F
#define SWZ16_(x) ((unsigned)__builtin_amdgcn_ds_swizzle((int)(x), 0x401F))

#if __has_builtin(__builtin_amdgcn_permlane16_swap)
#define HAVE_PL16 1
#else
#define HAVE_PL16 0
#endif

// 16-reg all-gather: depth-5 tree (pl16swap + row-local rors). Discovery
// (identical ops on the lane index) makes the exact permutation irrelevant.
__device__ __forceinline__ void gather_tree(unsigned v0, unsigned g[16]) {
#if HAVE_PL16
    unsigned v1 = DPP_(v0, CTRL_XOR2);
    auto sw = __builtin_amdgcn_permlane16_swap(v0, v1, false, false);
    unsigned s0 = (unsigned)sw[0], s1 = (unsigned)sw[1];
#else
    unsigned s0 = v0;
    unsigned s1 = SWZ16_(v0);
#endif
    g[0] = s0;                 g[1] = s1;
    g[2]  = DPP_(s0, 0x122);   g[3]  = DPP_(s1, 0x122);
    g[4]  = DPP_(s0, 0x124);   g[5]  = DPP_(s1, 0x124);
    g[6]  = DPP_(s0, 0x126);   g[7]  = DPP_(s1, 0x126);
    g[8]  = DPP_(s0, 0x128);   g[9]  = DPP_(s1, 0x128);
    g[10] = DPP_(s0, 0x12A);   g[11] = DPP_(s1, 0x12A);
    g[12] = DPP_(s0, 0x12C);   g[13] = DPP_(s1, 0x12C);
    g[14] = DPP_(s0, 0x12E);   g[15] = DPP_(s1, 0x12E);
}

__device__ __forceinline__ void waitflag(int* f) {
    while (__hip_atomic_load(f, __ATOMIC_ACQUIRE, __HIP_MEMORY_SCOPE_AGENT) == 0)
        __builtin_amdgcn_s_sleep(2);
}

// ---- Fused kernel: blocks 0-63 = per-batch xg producers (256 thr),
//      blocks 64-127 = per-batch single-wave scanners (round-13 structure).
// Producer writes xg2[b][j][t] (packed prescaled fp16 pairs) tile-by-tile
// (64 timesteps each) and releases a device-scope flag per tile; scanner
// acquire-waits one tile ahead and runs the proven scan loop unchanged.
__global__ __launch_bounds__(256) void lstm_fused2(const float* __restrict__ X,
                                                   const float* __restrict__ Wx,
                                                   const float* __restrict__ Wh,
                                                   const float* __restrict__ bias,
                                                   const float* __restrict__ Wd,
                                                   const float* __restrict__ bd,
                                                   float* __restrict__ out,
                                                   unsigned* __restrict__ xg2,
                                                   int* __restrict__ flags) {
    const int bid = blockIdx.x;

    if (bid < BB) {
        // ---------------- producer for batch `bid` ----------------
        __shared__ unsigned XLh[64][16];
        __shared__ unsigned WLh[16][128];
        const int tid = threadIdx.x;
        const int b = bid;
        const int j0 = (tid & 15) * 4;
        const int r0 = (tid >> 4) * 4;

        for (int tile = 0; tile < NTILE; ++tile) {
            const int trow0 = tile * 64;
            float acc[4][8];
#pragma unroll
            for (int r = 0; r < 4; ++r)
#pragma unroll
                for (int jj = 0; jj < 8; ++jj) acc[r][jj] = 0.f;

            for (int f0 = 0; f0 < FF; f0 += 32) {
                __syncthreads();
                {
                    const int jq = (tid & 31) * 4;
#pragma unroll
                    for (int qq = 0; qq < 2; ++qq) {
                        const int q = (tid >> 5) + qq * 8;
                        float4 wa = *(const float4*)(Wx + (size_t)(f0 + 2 * q) * GG + jq);
                        float4 wb = *(const float4*)(Wx + (size_t)(f0 + 2 * q + 1) * GG + jq);
                        WLh[q][jq + 0] = h2u(pkrtz(wa.x, wb.x));
                        WLh[q][jq + 1] = h2u(pkrtz(wa.y, wb.y));
                        WLh[q][jq + 2] = h2u(pkrtz(wa.z, wb.z));
                        WLh[q][jq + 3] = h2u(pkrtz(wa.w, wb.w));
                    }
                }
                {
                    int lin = tid * 4;
                    int row = lin >> 5, fi = lin & 31;
                    float4 x = *(const float4*)(X + ((size_t)b * TT + trow0 + row) * FF + f0 + fi);
                    XLh[row][(fi >> 1) + 0] = h2u(pkrtz(x.x, x.y));
                    XLh[row][(fi >> 1) + 1] = h2u(pkrtz(x.z, x.w));
                    lin = (tid + 256) * 4;
                    row = lin >> 5; fi = lin & 31;
                    x = *(const float4*)(X + ((size_t)b * TT + trow0 + row) * FF + f0 + fi);
                    XLh[row][(fi >> 1) + 0] = h2u(pkrtz(x.x, x.y));
                    XLh[row][(fi >> 1) + 1] = h2u(pkrtz(x.z, x.w));
                }
                __syncthreads();
#pragma unroll 4
                for (int q = 0; q < 16; ++q) {
                    half2_t xv[4];
#pragma unroll
                    for (int r = 0; r < 4; ++r) xv[r] = u2h(XLh[r0 + r][q]);
                    uint4 w0 = *(uint4*)&WLh[q][j0];
                    uint4 w1 = *(uint4*)&WLh[q][j0 + 64];
                    unsigned wj[8] = {w0.x, w0.y, w0.z, w0.w, w1.x, w1.y, w1.z, w1.w};
#pragma unroll
                    for (int r = 0; r < 4; ++r)
#pragma unroll
                        for (int jj = 0; jj < 8; ++jj)
                            acc[r][jj] = fdot2_(xv[r], u2h(wj[jj]), acc[r][jj]);
                }
            }
            const int t0 = trow0 + r0;
#pragma unroll
            for (int jj = 0; jj < 4; ++jj) {
                const int j = j0 + jj;
                const float bX = bias[j];
                const float bY = bias[j + 64];
                const float sY = (j < 32) ? S2f : S1f;
                uint4 o;
                o.x = h2u(pkrtz((acc[0][jj] + bX) * S1f, (acc[0][jj + 4] + bY) * sY));
                o.y = h2u(pkrtz((acc[1][jj] + bX) * S1f, (acc[1][jj + 4] + bY) * sY));
                o.z = h2u(pkrtz((acc[2][jj] + bX) * S1f, (acc[2][jj + 4] + bY) * sY));
                o.w = h2u(pkrtz((acc[3][jj] + bX) * S1f, (acc[3][jj + 4] + bY) * sY));
                *(uint4*)(xg2 + (size_t)(b * 64 + j) * TT + t0) = o;
            }
            // publish tile: flush this thread's stores, sync block, release flag
            __threadfence();
            __syncthreads();
            if (tid == 0)
                __hip_atomic_store(&flags[b * NTILE + tile], 1,
                                   __ATOMIC_RELEASE, __HIP_MEMORY_SCOPE_AGENT);
        }
        return;
    }

    // ---------------- scanner for batch `bid - 64` (wave 0 only) ----------
    if (threadIdx.x >= 64) return;
    const int l = threadIdx.x;
    const int m = l & 31;
    const bool lo = (l < HH);
    const int b = bid - BB;
    int* myflags = flags + b * NTILE;

    unsigned iv[16];
    gather_tree((unsigned)m, iv);

    const float scx = S1f;
    const float scy = lo ? S2f : S1f;
    half2_t whx[16], why[16];
#pragma unroll
    for (int r = 0; r < 16; ++r) {
        const int p  = (int)(iv[r] & 31u);
        const int p2 = p ^ 1;
        whx[r] = pkrtz(Wh[p * GG + l] * scx,       Wh[p2 * GG + l] * scx);
        why[r] = pkrtz(Wh[p * GG + l + 64] * scy,  Wh[p2 * GG + l + 64] * scy);
    }

    const float A1 = lo ? 2.f : 1.f;
    const float B1 = lo ? -1.f : 0.f;

    float h = 0.f, c = 0.f;

    const unsigned* pX = xg2 + (size_t)(b * 64 + l) * TT;

    waitflag(myflags);         // tile 0 ready
    uint4 cur = *(const uint4*)(pX);
    uint4 nxt = *(const uint4*)(pX + 4);

    auto step = [&](unsigned w) __attribute__((always_inline)) {
        half2_t xv = u2h(w);
        float xi = (float)xv[0];
        float xy = (float)xv[1];
        unsigned hn = DPP_(__float_as_uint(h), CTRL_XOR1);
        unsigned g0 = h2u(pkrtz(h, __uint_as_float(hn)));
        unsigned g[16];
        gather_tree(g0, g);
        float ax[4] = {xi, 0.f, 0.f, 0.f};
        float ay[4] = {xy, 0.f, 0.f, 0.f};
#pragma unroll
        for (int r = 0; r < 16; ++r) {
            half2_t hp = u2h(g[r]);
            ax[r & 3] = fdot2_(hp, whx[r], ax[r & 3]);
            ay[r & 3] = fdot2_(hp, why[r], ay[r & 3]);
        }
        float a0 = (ax[0] + ax[1]) + (ax[2] + ax[3]);
        float a1 = (ay[0] + ay[1]) + (ay[2] + ay[3]);
        float act0 = rcp_(1.f + exp2_(a0));
        float act1 = fmaf(A1, rcp_(1.f + exp2_(a1)), B1);
        auto sw0 = __builtin_amdgcn_permlane32_swap(__float_as_uint(act0),
                                                    __float_as_uint(act0), false, false);
        auto sw1 = __builtin_amdgcn_permlane32_swap(__float_as_uint(act1),
                                                    __float_as_uint(act1), false, false);
        float i_all = __uint_as_float(sw0[0]);
        float f_all = __uint_as_float(sw0[1]);
        float g_all = __uint_as_float(sw1[0]);
        float o_all = __uint_as_float(sw1[1]);
        c = fmaf(f_all, c, i_all * g_all);
        float tc = fmaf(2.f, rcp_(1.f + exp2_(c * S2f)), -1.f);
        h = o_all * tc;
    };

    for (int k = 0; k < NTILE; ++k) {
        // stay one tile ahead so in-chunk prefetch (t4+8) is always safe
        waitflag(myflags + (k + 1 < NTILE ? k + 1 : NTILE - 1));
#pragma unroll 1
        for (int g4 = 0; g4 < 16; ++g4) {
            const int t4 = k * 64 + g4 * 4;
            uint4 u = cur;
            cur = nxt;
            if (t4 + 8 < TT) nxt = *(const uint4*)(pX + t4 + 8);
            step(u.x);
            step(u.y);
            step(u.z);
            step(u.w);
        }
    }

    float contrib = h * Wd[m];
#pragma unroll
    for (int off = 32; off >= 1; off >>= 1)
        contrib += __shfl_xor(contrib, off, 64);
    if (l == 0) out[b] = fmaf(0.5f, contrib, bd[0]);
}

extern "C" void kernel_launch(void* const* d_in, const int* in_sizes, int n_in,
                              void* d_out, int out_size, void* d_ws, size_t ws_size,
                              hipStream_t stream) {
    const float* X    = (const float*)d_in[0];
    const float* Wx   = (const float*)d_in[1];
    const float* Wh   = (const float*)d_in[2];
    const float* bias = (const float*)d_in[3];
    const float* Wd   = (const float*)d_in[4];
    const float* bd   = (const float*)d_in[5];
    float* out = (float*)d_out;
    unsigned* xg2 = (unsigned*)d_ws;                       // 32 MB
    int* flags = (int*)((char*)d_ws + FLAG_OFF);           // 8 KB

    hipMemsetAsync(flags, 0, BB * NTILE * sizeof(int), stream);
    hipLaunchKernelGGL(lstm_fused2, dim3(2 * BB), dim3(256), 0, stream,
                       X, Wx, Wh, bias, Wd, bd, out, xg2, flags);
}

// Round 17
// 487.309 us; speedup vs baseline: 1.5513x; 1.2230x over previous
//
#include <hip/hip_runtime.h>
#include <math.h>

#define BB 64
#define TT 2048
#define FF 128
#define HH 32
#define GG 128  // 4*H

// gate-column prescale: sigma(a) = rcp(1 + exp2(S1*a)), tanh(a) = 2*rcp(1+exp2(S2*a))-1
#define S1f (-1.4426950408889634f)  // -log2(e)
#define S2f (-2.8853900817779268f)  // -2*log2(e)

typedef _Float16 half2_t __attribute__((ext_vector_type(2)));
typedef _Float16 half8_t __attribute__((ext_vector_type(8)));
typedef float floatx4 __attribute__((ext_vector_type(4)));

__device__ __forceinline__ unsigned h2u(half2_t v) {
    unsigned u; __builtin_memcpy(&u, &v, 4); return u;
}
__device__ __forceinline__ half2_t u2h(unsigned u) {
    half2_t v; __builtin_memcpy(&v, &u, 4); return v;
}
__device__ __forceinline__ half2_t pkrtz(float a, float b) {
    auto r = __builtin_amdgcn_cvt_pkrtz(a, b);  // __fp16 vec2, same bits
    half2_t v; __builtin_memcpy(&v, &r, 4); return v;
}
__device__ __forceinline__ half8_t mk8(unsigned a, unsigned b, unsigned c, unsigned d) {
    unsigned v[4] = {a, b, c, d};
    half8_t r; __builtin_memcpy(&r, v, 16); return r;
}
__device__ __forceinline__ float rcp_(float x) { return __builtin_amdgcn_rcpf(x); }
__device__ __forceinline__ float exp2_(float x) { return __builtin_amdgcn_exp2f(x); }
__device__ __forceinline__ float fdot2_(half2_t a, half2_t b, float c) {
    return __builtin_amdgcn_fdot2(a, b, c, false);
}

// DPP lane shuffles; bound_ctrl=1, all rows/banks
#define DPP_(x, ctrl) \
    ((unsigned)__builtin_amdgcn_mov_dpp((int)(x), (ctrl), 0xF, 0xF, true))
#define CTRL_XOR1 0xB1  // quad_perm [1,0,3,2]

// ---- Kernel 1: xg2[b][j][t] = half2( S*(X@Wx+b)[col j], S*(X@Wx+b)[col j+64] )
// fp16-fdot2 inner loop: X and Wx staged as packed K-pairs in LDS. (round-13)
__global__ __launch_bounds__(256) void xg_gemm(const float* __restrict__ X,
                                               const float* __restrict__ Wx,
                                               const float* __restrict__ bias,
                                               unsigned* __restrict__ xg2) {
    __shared__ unsigned XLh[64][16];
    __shared__ unsigned WLh[16][128];
    const int tid = threadIdx.x;
    const int row0 = blockIdx.x * 64;
    const int j0 = (tid & 15) * 4;
    const int r0 = (tid >> 4) * 4;

    float acc[4][8];
#pragma unroll
    for (int r = 0; r < 4; ++r)
#pragma unroll
        for (int jj = 0; jj < 8; ++jj) acc[r][jj] = 0.f;

    for (int f0 = 0; f0 < FF; f0 += 32) {
        __syncthreads();
        {
            const int jq = (tid & 31) * 4;
#pragma unroll
            for (int qq = 0; qq < 2; ++qq) {
                const int q = (tid >> 5) + qq * 8;
                float4 wa = *(const float4*)(Wx + (size_t)(f0 + 2 * q) * GG + jq);
                float4 wb = *(const float4*)(Wx + (size_t)(f0 + 2 * q + 1) * GG + jq);
                WLh[q][jq + 0] = h2u(pkrtz(wa.x, wb.x));
                WLh[q][jq + 1] = h2u(pkrtz(wa.y, wb.y));
                WLh[q][jq + 2] = h2u(pkrtz(wa.z, wb.z));
                WLh[q][jq + 3] = h2u(pkrtz(wa.w, wb.w));
            }
        }
        {
            int lin = tid * 4;
            int row = lin >> 5, fi = lin & 31;
            float4 x = *(const float4*)(X + (size_t)(row0 + row) * FF + f0 + fi);
            XLh[row][(fi >> 1) + 0] = h2u(pkrtz(x.x, x.y));
            XLh[row][(fi >> 1) + 1] = h2u(pkrtz(x.z, x.w));
            lin = (tid + 256) * 4;
            row = lin >> 5; fi = lin & 31;
            x = *(const float4*)(X + (size_t)(row0 + row) * FF + f0 + fi);
            XLh[row][(fi >> 1) + 0] = h2u(pkrtz(x.x, x.y));
            XLh[row][(fi >> 1) + 1] = h2u(pkrtz(x.z, x.w));
        }
        __syncthreads();
#pragma unroll 4
        for (int q = 0; q < 16; ++q) {
            half2_t xv[4];
#pragma unroll
            for (int r = 0; r < 4; ++r) xv[r] = u2h(XLh[r0 + r][q]);
            uint4 w0 = *(uint4*)&WLh[q][j0];
            uint4 w1 = *(uint4*)&WLh[q][j0 + 64];
            unsigned wj[8] = {w0.x, w0.y, w0.z, w0.w, w1.x, w1.y, w1.z, w1.w};
#pragma unroll
            for (int r = 0; r < 4; ++r)
#pragma unroll
                for (int jj = 0; jj < 8; ++jj)
                    acc[r][jj] = fdot2_(xv[r], u2h(wj[jj]), acc[r][jj]);
        }
    }
    const int b  = row0 >> 11;
    const int t0 = (row0 & 2047) + r0;
#pragma unroll
    for (int jj = 0; jj < 4; ++jj) {
        const int j = j0 + jj;
        const float bX = bias[j];
        const float bY = bias[j + 64];
        const float sY = (j < 32) ? S2f : S1f;
        uint4 o;
        o.x = h2u(pkrtz((acc[0][jj] + bX) * S1f, (acc[0][jj + 4] + bY) * sY));
        o.y = h2u(pkrtz((acc[1][jj] + bX) * S1f, (acc[1][jj + 4] + bY) * sY));
        o.z = h2u(pkrtz((acc[2][jj] + bX) * S1f, (acc[2][jj + 4] + bY) * sY));
        o.w = h2u(pkrtz((acc[3][jj] + bX) * S1f, (acc[3][jj + 4] + bY) * sY));
        *(uint4*)(xg2 + (size_t)(b * 64 + j) * TT + t0) = o;
    }
}

// ---- Kernel 2: single-wave LSTM scan, MFMA recurrent matvec ---------------
// One block (one wave) per batch element. Lane l owns gate columns l, l+64;
// h[l&31], c[l&31] replicated across halves.
// Per step: h -> fp16 pairs -> 4 ds_bpermute build the A fragment (A = h in
// every row), 8 mfma_f32_16x16x32_f16 compute all 128 gate preacts; lane l
// holds col l&15 of every accumulator (C/D: col=lane&15) so extraction is a
// 6-cndmask select. B fragments = prescaled Wh columns (canonical layout:
// lane&15 = col, lane>>4 = k-block, 8 contiguous k per lane).
__global__ __launch_bounds__(64) void lstm_rec(const unsigned* __restrict__ xg2,
                                               const float* __restrict__ Wh,
                                               const float* __restrict__ Wd,
                                               const float* __restrict__ bd,
                                               float* __restrict__ out) {
    const int l = threadIdx.x;  // 0..63
    const int m = l & 31;
    const int q = l >> 4;       // k-block 0..3
    const int cl = l & 15;      // local col within a 16-col mfma
    const bool lo = (l < HH);
    const int b = blockIdx.x;

    // ---- B fragments: 8 mfmas x 4 packed k-pairs (prescaled Wh columns) ---
    unsigned wb[8][4];
#pragma unroll
    for (int t = 0; t < 8; ++t) {
        const int col = 16 * t + cl;
        const float sc = (col >= 64 && col < 96) ? S2f : S1f;
#pragma unroll
        for (int j = 0; j < 4; ++j) {
            const int k = 8 * q + 2 * j;
            wb[t][j] = h2u(pkrtz(Wh[(size_t)k * GG + col] * sc,
                                 Wh[(size_t)(k + 1) * GG + col] * sc));
        }
    }

    // bpermute byte-addresses: A-reg j reads pair (4q+j) from lane 8q+2j
    int ba0 = (8 * q + 0) * 4;
    int ba1 = (8 * q + 2) * 4;
    int ba2 = (8 * q + 4) * 4;
    int ba3 = (8 * q + 6) * 4;

    // per-lane affine for act1: tanh = 2*s-1 (lo), sigmoid = s (hi)
    const float A1 = lo ? 2.f : 1.f;
    const float B1 = lo ? -1.f : 0.f;
    const bool sel16 = (l & 16) != 0;
    const bool sel32 = (l & 32) != 0;

    float h = 0.f;  // lane l: h[m]
    float c = 0.f;  // lane l: c[m]

    const unsigned* pX = xg2 + (size_t)(b * 64 + l) * TT;

    uint4 cur = *(const uint4*)(pX);
    uint4 nxt = *(const uint4*)(pX + 4);

    const floatx4 zz = {0.f, 0.f, 0.f, 0.f};

    auto step = [&](unsigned w) __attribute__((always_inline)) {
        half2_t xv = u2h(w);
        float xi = (float)xv[0];   // prescaled preact, col l   (i|f)
        float xy = (float)xv[1];   // prescaled preact, col l+64 (g|o)

        // ---- A fragment: h packed pairs, gathered per k-block ----
        unsigned hn = DPP_(__float_as_uint(h), CTRL_XOR1);
        unsigned hp = h2u(pkrtz(h, __uint_as_float(hn)));  // even lane 2p: (h[2p],h[2p+1])
        unsigned a0 = (unsigned)__builtin_amdgcn_ds_bpermute(ba0, (int)hp);
        unsigned a1 = (unsigned)__builtin_amdgcn_ds_bpermute(ba1, (int)hp);
        unsigned a2 = (unsigned)__builtin_amdgcn_ds_bpermute(ba2, (int)hp);
        unsigned a3 = (unsigned)__builtin_amdgcn_ds_bpermute(ba3, (int)hp);
        half8_t A = mk8(a0, a1, a2, a3);

        // ---- 8 MFMAs: acc[t] covers gate cols 16t..16t+15 ----
        floatx4 acc0 = __builtin_amdgcn_mfma_f32_16x16x32_f16(A, mk8(wb[0][0], wb[0][1], wb[0][2], wb[0][3]), zz, 0, 0, 0);
        floatx4 acc1 = __builtin_amdgcn_mfma_f32_16x16x32_f16(A, mk8(wb[1][0], wb[1][1], wb[1][2], wb[1][3]), zz, 0, 0, 0);
        floatx4 acc2 = __builtin_amdgcn_mfma_f32_16x16x32_f16(A, mk8(wb[2][0], wb[2][1], wb[2][2], wb[2][3]), zz, 0, 0, 0);
        floatx4 acc3 = __builtin_amdgcn_mfma_f32_16x16x32_f16(A, mk8(wb[3][0], wb[3][1], wb[3][2], wb[3][3]), zz, 0, 0, 0);
        floatx4 acc4 = __builtin_amdgcn_mfma_f32_16x16x32_f16(A, mk8(wb[4][0], wb[4][1], wb[4][2], wb[4][3]), zz, 0, 0, 0);
        floatx4 acc5 = __builtin_amdgcn_mfma_f32_16x16x32_f16(A, mk8(wb[5][0], wb[5][1], wb[5][2], wb[5][3]), zz, 0, 0, 0);
        floatx4 acc6 = __builtin_amdgcn_mfma_f32_16x16x32_f16(A, mk8(wb[6][0], wb[6][1], wb[6][2], wb[6][3]), zz, 0, 0, 0);
        floatx4 acc7 = __builtin_amdgcn_mfma_f32_16x16x32_f16(A, mk8(wb[7][0], wb[7][1], wb[7][2], wb[7][3]), zz, 0, 0, 0);

        // ---- extract: lane l holds col l&15 of every acc (any row) ----
        float s0a = sel16 ? acc1[0] : acc0[0];
        float s0b = sel16 ? acc3[0] : acc2[0];
        float a0v = (sel32 ? s0b : s0a) + xi;   // preact col l (i|f), prescaled
        float s1a = sel16 ? acc5[0] : acc4[0];
        float s1b = sel16 ? acc7[0] : acc6[0];
        float a1v = (sel32 ? s1b : s1a) + xy;   // preact col l+64 (g|o), prescaled

        // ---- activations (round-13 path) ----
        float act0 = rcp_(1.f + exp2_(a0v));
        float act1 = fmaf(A1, rcp_(1.f + exp2_(a1v)), B1);
        auto sw0 = __builtin_amdgcn_permlane32_swap(__float_as_uint(act0),
                                                    __float_as_uint(act0), false, false);
        auto sw1 = __builtin_amdgcn_permlane32_swap(__float_as_uint(act1),
                                                    __float_as_uint(act1), false, false);
        float i_all = __uint_as_float(sw0[0]);
        float f_all = __uint_as_float(sw0[1]);
        float g_all = __uint_as_float(sw1[0]);
        float o_all = __uint_as_float(sw1[1]);
        c = fmaf(f_all, c, i_all * g_all);
        float tc = fmaf(2.f, rcp_(1.f + exp2_(c * S2f)), -1.f);  // tanh(c)
        h = o_all * tc;
    };

#pragma unroll 1
    for (int t4 = 0; t4 < TT; t4 += 4) {
        uint4 u = cur;
        cur = nxt;
        if (t4 + 8 < TT) nxt = *(const uint4*)(pX + t4 + 8);
        step(u.x);
        step(u.y);
        step(u.z);
        step(u.w);
    }

    // out[b] = h_T @ Wd + bd   (each h[k] appears twice across 64 lanes)
    float contrib = h * Wd[m];
#pragma unroll
    for (int off = 32; off >= 1; off >>= 1)
        contrib += __shfl_xor(contrib, off, 64);
    if (l == 0) out[b] = fmaf(0.5f, contrib, bd[0]);
}

extern "C" void kernel_launch(void* const* d_in, const int* in_sizes, int n_in,
                              void* d_out, int out_size, void* d_ws, size_t ws_size,
                              hipStream_t stream) {
    const float* X    = (const float*)d_in[0];
    const float* Wx   = (const float*)d_in[1];
    const float* Wh   = (const float*)d_in[2];
    const float* bias = (const float*)d_in[3];
    const float* Wd   = (const float*)d_in[4];
    const float* bd   = (const float*)d_in[5];
    float* out = (float*)d_out;
    unsigned* xg2 = (unsigned*)d_ws;  // [64][64][2048] half2-pairs = 32 MB

    hipLaunchKernelGGL(xg_gemm, dim3((BB * TT) / 64), dim3(256), 0, stream,
                       X, Wx, bias, xg2);
    hipLaunchKernelGGL(lstm_rec, dim3(BB), dim3(64), 0, stream,
                       xg2, Wh, Wd, bd, out);
}